// Round 2
// baseline (193.180 us; speedup 1.0000x reference)
//
#include <hip/hip_runtime.h>
#include <math.h>

// Problem constants (fixed by reference)
#define B_ 8
#define N_ 384
#define D_ 256
#define H_ 1024

#define TILE 64
#define KC 16
#define LP 68   // padded LDS leading dim (floats): 68%4==0 keeps float4 aligned; 2-way bank aliasing only

// box_num is logically int64 in the reference, but the harness may hand it to
// us as int32. Both layouts are distinguishable at runtime: box_num >= 1
// always, so in an int64 little-endian layout the odd int32 words (high
// halves) are all zero, which an int32 layout can never produce.
__device__ inline int load_boxnum(const int* __restrict__ p, int b) {
    bool is64 = ((p[1] | p[3] | p[5] | p[7]) == 0);
    return is64 ? p[2 * b] : p[b];
}

// ---------------- sum(learn_w) ----------------
__global__ __launch_bounds__(64) void sumw_kernel(const float* __restrict__ w,
                                                  float* __restrict__ out) {
    int t = threadIdx.x;
    float v = w[t] + w[t + 64] + w[t + 128] + w[t + 192];
    #pragma unroll
    for (int off = 32; off > 0; off >>= 1) v += __shfl_xor(v, off);
    if (t == 0) out[0] = v;
}

// ---------------- GEMM: C[m,n] = act(sum_k A[m,k]*Bt[n,k] + bias[n]) ----------------
// A: (M,K) row-major, Bt: (Nn,K) row-major (i.e. B transposed), both K-contiguous.
__global__ __launch_bounds__(256) void gemm_bt(const float* __restrict__ A,
                                               const float* __restrict__ Bt,
                                               const float* __restrict__ bias,
                                               float* __restrict__ C,
                                               int Nn, int K, int do_relu) {
    __shared__ __align__(16) float As[KC * LP];
    __shared__ __align__(16) float Bs[KC * LP];
    const int tx = threadIdx.x & 15, ty = threadIdx.x >> 4;
    const int n0 = blockIdx.x * TILE, m0 = blockIdx.y * TILE;
    const int lr = threadIdx.x >> 2;          // 0..63: tile row
    const int lk = (threadIdx.x & 3) * 4;     // 0,4,8,12: k offset
    const float* Ap = A + (size_t)(m0 + lr) * K + lk;
    const float* Bp = Bt + (size_t)(n0 + lr) * K + lk;
    float acc[4][4] = {};
    for (int k0 = 0; k0 < K; k0 += KC) {
        float4 av = *(const float4*)(Ap + k0);
        float4 bv = *(const float4*)(Bp + k0);
        __syncthreads();
        As[(lk + 0) * LP + lr] = av.x; As[(lk + 1) * LP + lr] = av.y;
        As[(lk + 2) * LP + lr] = av.z; As[(lk + 3) * LP + lr] = av.w;
        Bs[(lk + 0) * LP + lr] = bv.x; Bs[(lk + 1) * LP + lr] = bv.y;
        Bs[(lk + 2) * LP + lr] = bv.z; Bs[(lk + 3) * LP + lr] = bv.w;
        __syncthreads();
        #pragma unroll
        for (int kk = 0; kk < KC; kk++) {
            float4 a4 = *(const float4*)&As[kk * LP + ty * 4];
            float4 b4 = *(const float4*)&Bs[kk * LP + tx * 4];
            float a[4] = {a4.x, a4.y, a4.z, a4.w};
            float b[4] = {b4.x, b4.y, b4.z, b4.w};
            #pragma unroll
            for (int ii = 0; ii < 4; ii++)
                #pragma unroll
                for (int jj = 0; jj < 4; jj++)
                    acc[ii][jj] = fmaf(a[ii], b[jj], acc[ii][jj]);
        }
    }
    #pragma unroll
    for (int ii = 0; ii < 4; ii++) {
        int row = m0 + ty * 4 + ii;
        #pragma unroll
        for (int jj = 0; jj < 4; jj++) {
            int col = n0 + tx * 4 + jj;
            float v = acc[ii][jj] + bias[col];
            if (do_relu) v = fmaxf(v, 0.f);
            C[(size_t)row * Nn + col] = v;
        }
    }
}

// ---------------- pairwise weighted L1 + mask + leaky ----------------
// dist[b,i,j] = leaky( sum_d w[d]*|xh[b,i,d]-xh[b,j,d]| - (pair_invalid ? sumw : 0) )
// learn_w >= 0 (uniform(0,1) by construction) -> w*|a-b| == |w*a - w*b|: prescale rows by w.
__global__ __launch_bounds__(256) void dist_kernel(const float* __restrict__ xhat,
                                                   const float* __restrict__ w,
                                                   const int* __restrict__ box_num,
                                                   const float* __restrict__ sumw_p,
                                                   float* __restrict__ dist) {
    __shared__ __align__(16) float Xi[KC * LP];
    __shared__ __align__(16) float Xj[KC * LP];
    const int b = blockIdx.z;
    const int i0 = blockIdx.y * TILE, j0 = blockIdx.x * TILE;
    const int tx = threadIdx.x & 15, ty = threadIdx.x >> 4;
    const int lr = threadIdx.x >> 2;
    const int lk = (threadIdx.x & 3) * 4;
    const float* xb = xhat + (size_t)b * N_ * D_;
    const float* Xip = xb + (size_t)(i0 + lr) * D_ + lk;
    const float* Xjp = xb + (size_t)(j0 + lr) * D_ + lk;
    float acc[4][4] = {};
    for (int k0 = 0; k0 < D_; k0 += KC) {
        float4 xiv = *(const float4*)(Xip + k0);
        float4 xjv = *(const float4*)(Xjp + k0);
        float4 wv  = *(const float4*)(w + k0 + lk);
        xiv.x *= wv.x; xiv.y *= wv.y; xiv.z *= wv.z; xiv.w *= wv.w;
        xjv.x *= wv.x; xjv.y *= wv.y; xjv.z *= wv.z; xjv.w *= wv.w;
        __syncthreads();
        Xi[(lk + 0) * LP + lr] = xiv.x; Xi[(lk + 1) * LP + lr] = xiv.y;
        Xi[(lk + 2) * LP + lr] = xiv.z; Xi[(lk + 3) * LP + lr] = xiv.w;
        Xj[(lk + 0) * LP + lr] = xjv.x; Xj[(lk + 1) * LP + lr] = xjv.y;
        Xj[(lk + 2) * LP + lr] = xjv.z; Xj[(lk + 3) * LP + lr] = xjv.w;
        __syncthreads();
        #pragma unroll
        for (int kk = 0; kk < KC; kk++) {
            float4 a4 = *(const float4*)&Xi[kk * LP + ty * 4];
            float4 b4 = *(const float4*)&Xj[kk * LP + tx * 4];
            float a[4] = {a4.x, a4.y, a4.z, a4.w};
            float b[4] = {b4.x, b4.y, b4.z, b4.w};
            #pragma unroll
            for (int ii = 0; ii < 4; ii++)
                #pragma unroll
                for (int jj = 0; jj < 4; jj++)
                    acc[ii][jj] += fabsf(a[ii] - b[jj]);   // v_sub + v_add(abs mod)
        }
    }
    const int bn = load_boxnum(box_num, b);
    const float sumw = sumw_p[0];
    #pragma unroll
    for (int ii = 0; ii < 4; ii++) {
        int i = i0 + ty * 4 + ii;
        bool vi = i < bn;
        #pragma unroll
        for (int jj = 0; jj < 4; jj++) {
            int j = j0 + tx * 4 + jj;
            float v = acc[ii][jj];
            if (!(vi && (j < bn))) v -= sumw;
            v = v > 0.f ? v : 0.01f * v;   // leaky_relu(0.01)
            dist[((size_t)b * N_ + i) * N_ + j] = v;
        }
    }
}

// ---------------- row softmax: one wave per (b,i) row ----------------
__global__ __launch_bounds__(64) void softmax_kernel(float* __restrict__ sa,
                                                     const float* __restrict__ adj) {
    const int row = blockIdx.x;        // b*N + i
    const int t = threadIdx.x;
    float* prow = sa + (size_t)row * N_;
    const float* arow = adj + (size_t)row * N_;
    float v[6];
    float m = -1e30f;
    #pragma unroll
    for (int q = 0; q < 6; q++) { v[q] = prow[t + q * 64]; m = fmaxf(m, v[q]); }
    #pragma unroll
    for (int off = 32; off > 0; off >>= 1) m = fmaxf(m, __shfl_xor(m, off));
    float e[6];
    float s = 0.f;
    #pragma unroll
    for (int q = 0; q < 6; q++) { e[q] = arow[t + q * 64] * expf(v[q] - m); s += e[q]; }
    #pragma unroll
    for (int off = 32; off > 0; off >>= 1) s += __shfl_xor(s, off);
    float inv = 1.0f / s;
    #pragma unroll
    for (int q = 0; q < 6; q++) prow[t + q * 64] = e[q] * inv + 1e-10f;
}

extern "C" void kernel_launch(void* const* d_in, const int* in_sizes, int n_in,
                              void* d_out, int out_size, void* d_ws, size_t ws_size,
                              hipStream_t stream) {
    const float* x       = (const float*)d_in[0];
    const float* adj     = (const float*)d_in[1];
    const int*   box_num = (const int*)d_in[2];
    const float* fc1_w   = (const float*)d_in[3];
    const float* fc1_b   = (const float*)d_in[4];
    const float* fc2_w   = (const float*)d_in[5];
    const float* fc2_b   = (const float*)d_in[6];
    const float* learn_w = (const float*)d_in[7];

    float* soft_adj = (float*)d_out;                              // B*N*N
    float* xhat     = (float*)d_out + (size_t)B_ * N_ * N_;       // B*N*D

    float* sumw = (float*)d_ws;            // 1 float (256-float slot for alignment)
    float* c1   = (float*)d_ws + 256;      // relu(fc1(x)) chunk buffer

    const int BN = B_ * N_;                // 3072
    size_t avail = ws_size / sizeof(float);
    avail = (avail > 256) ? avail - 256 : 0;
    long long mr = (long long)(avail / H_) & ~63LL;   // rows of c1 that fit, multiple of 64
    int max_rows = (int)((mr > BN) ? BN : mr);
    if (max_rows < 64) max_rows = 64;                 // ws is expected to cover at least one chunk

    sumw_kernel<<<1, 64, 0, stream>>>(learn_w, sumw);

    for (int m0 = 0; m0 < BN; m0 += max_rows) {
        int rows = BN - m0; if (rows > max_rows) rows = max_rows;
        dim3 g1(H_ / TILE, rows / TILE);
        gemm_bt<<<g1, 256, 0, stream>>>(x + (size_t)m0 * D_, fc1_w, fc1_b, c1, H_, D_, 1);
        dim3 g2(D_ / TILE, rows / TILE);
        gemm_bt<<<g2, 256, 0, stream>>>(c1, fc2_w, fc2_b, xhat + (size_t)m0 * D_, D_, H_, 0);
    }

    dim3 gd(N_ / TILE, N_ / TILE, B_);
    dist_kernel<<<gd, 256, 0, stream>>>(xhat, learn_w, box_num, sumw, soft_adj);

    softmax_kernel<<<BN, 64, 0, stream>>>(soft_adj, adj);
}

// Round 3
// 156.876 us; speedup vs baseline: 1.2314x; 1.2314x over previous
//
#include <hip/hip_runtime.h>
#include <math.h>

// Problem constants (fixed by reference)
#define B_ 8
#define N_ 384
#define D_ 256
#define H_ 1024

typedef __bf16 bh;
typedef __bf16 bf16x8 __attribute__((ext_vector_type(8)));
typedef float  f32x4  __attribute__((ext_vector_type(4)));

#define LDK 40   // LDS row stride in bf16 (32 data + 8 pad): 80 B = 5*16 B -> b128-aligned, 2-way banks (free)

// split fp32 -> hi + lo bf16 (3xbf16 trick: a*b ~= ah*bh + ah*bl + al*bh, rel err ~2^-16)
__device__ inline void split2(float v, bh& h, bh& l) {
    h = (bh)v;
    l = (bh)(v - (float)h);
}

// box_num is logically int64; harness may hand int32. box_num >= 1 always, so
// int64-LE layout has all odd words zero -> runtime-detectable.
__device__ inline int load_boxnum(const int* __restrict__ p, int b) {
    bool is64 = ((p[1] | p[3] | p[5] | p[7]) == 0);
    return is64 ? p[2 * b] : p[b];
}

// ---------------- GEMM1: c1 = relu(x @ fc1_w^T + fc1_b), output split hi/lo bf16 ----------------
// 64x64 tile, 256 thr = 4 waves (2x2 of 32x32), BK=32, split-bf16 MFMA.
__global__ __launch_bounds__(256) void gemm1_kernel(
        const float* __restrict__ A,     // (rows,256) fp32
        const float* __restrict__ W,     // (1024,256) fp32, k-contiguous rows
        const float* __restrict__ bias,  // (1024)
        bh* __restrict__ Ch, bh* __restrict__ Cl)  // (rows,1024) each
{
    __shared__ __align__(16) bh AhS[64 * LDK], AlS[64 * LDK], WhS[64 * LDK], WlS[64 * LDK];
    const int tid = threadIdx.x;
    const int m0 = blockIdx.y * 64, n0 = blockIdx.x * 64;
    const int r = tid >> 2, kq = (tid & 3) * 8;       // staging: row, k-offset
    const int lane = tid & 63, wv_ = tid >> 6;
    const int wm = (wv_ & 1) * 32, wn = (wv_ >> 1) * 32;
    const int l15 = lane & 15, q = lane >> 4;

    f32x4 acc[2][2] = {};
    for (int k0 = 0; k0 < 256; k0 += 32) {
        const float* ap = A + (size_t)(m0 + r) * 256 + k0 + kq;
        const float* wp = W + (size_t)(n0 + r) * 256 + k0 + kq;
        float4 a0 = *(const float4*)ap;
        float4 a1 = *(const float4*)(ap + 4);
        float4 w0 = *(const float4*)wp;
        float4 w1 = *(const float4*)(wp + 4);
        float av[8] = {a0.x, a0.y, a0.z, a0.w, a1.x, a1.y, a1.z, a1.w};
        float wf[8] = {w0.x, w0.y, w0.z, w0.w, w1.x, w1.y, w1.z, w1.w};
        bf16x8 ah, al, wh, wl;
        #pragma unroll
        for (int i = 0; i < 8; i++) {
            bh h, l;
            split2(av[i], h, l); ah[i] = h; al[i] = l;
            split2(wf[i], h, l); wh[i] = h; wl[i] = l;
        }
        __syncthreads();
        *(bf16x8*)&AhS[r * LDK + kq] = ah;  *(bf16x8*)&AlS[r * LDK + kq] = al;
        *(bf16x8*)&WhS[r * LDK + kq] = wh;  *(bf16x8*)&WlS[r * LDK + kq] = wl;
        __syncthreads();
        bf16x8 fah[2], fal[2], fwh[2], fwl[2];
        #pragma unroll
        for (int mi = 0; mi < 2; mi++) {
            int row = wm + mi * 16 + l15;
            fah[mi] = *(const bf16x8*)&AhS[row * LDK + q * 8];
            fal[mi] = *(const bf16x8*)&AlS[row * LDK + q * 8];
        }
        #pragma unroll
        for (int ni = 0; ni < 2; ni++) {
            int row = wn + ni * 16 + l15;
            fwh[ni] = *(const bf16x8*)&WhS[row * LDK + q * 8];
            fwl[ni] = *(const bf16x8*)&WlS[row * LDK + q * 8];
        }
        #pragma unroll
        for (int mi = 0; mi < 2; mi++)
            #pragma unroll
            for (int ni = 0; ni < 2; ni++) {
                acc[mi][ni] = __builtin_amdgcn_mfma_f32_16x16x32_bf16(fah[mi], fwh[ni], acc[mi][ni], 0, 0, 0);
                acc[mi][ni] = __builtin_amdgcn_mfma_f32_16x16x32_bf16(fah[mi], fwl[ni], acc[mi][ni], 0, 0, 0);
                acc[mi][ni] = __builtin_amdgcn_mfma_f32_16x16x32_bf16(fal[mi], fwh[ni], acc[mi][ni], 0, 0, 0);
            }
    }
    // epilogue: C/D layout col=lane&15, row=(lane>>4)*4+reg [m89/m91 verified]
    #pragma unroll
    for (int ni = 0; ni < 2; ni++) {
        int col = n0 + wn + ni * 16 + l15;
        float bb = bias[col];
        #pragma unroll
        for (int mi = 0; mi < 2; mi++)
            #pragma unroll
            for (int reg = 0; reg < 4; reg++) {
                int row = m0 + wm + mi * 16 + q * 4 + reg;
                float v = fmaxf(acc[mi][ni][reg] + bb, 0.f);
                bh h, l; split2(v, h, l);
                size_t off = (size_t)row * H_ + col;
                Ch[off] = h; Cl[off] = l;
            }
    }
}

// ---------------- GEMM2: xhat = c1 @ fc2_w^T + fc2_b, fp32 out ----------------
// 64x32 tile, 128 thr = 2 waves (stacked in m), BK=32, A pre-split.
__global__ __launch_bounds__(128) void gemm2_kernel(
        const bh* __restrict__ Ah_, const bh* __restrict__ Al_,  // (rows,1024)
        const float* __restrict__ W,     // (256,1024) fp32
        const float* __restrict__ bias,  // (256)
        float* __restrict__ C)           // (rows,256)
{
    __shared__ __align__(16) bh AhS[64 * LDK], AlS[64 * LDK], WhS[32 * LDK], WlS[32 * LDK];
    const int tid = threadIdx.x;
    const int m0 = blockIdx.y * 64, n0 = blockIdx.x * 32;
    const int lane = tid & 63, wv_ = tid >> 6;        // wave 0/1
    const int wm = wv_ * 32;
    const int l15 = lane & 15, q = lane >> 4;
    const int ra = tid >> 1, ka = (tid & 1) * 16;     // A staging: 64 rows x 32 k
    const int rw = tid >> 2, kw = (tid & 3) * 8;      // W staging: 32 rows x 32 k

    f32x4 acc[2][2] = {};
    for (int k0 = 0; k0 < 1024; k0 += 32) {
        const bh* ahp = Ah_ + (size_t)(m0 + ra) * H_ + k0 + ka;
        const bh* alp = Al_ + (size_t)(m0 + ra) * H_ + k0 + ka;
        bf16x8 h0 = *(const bf16x8*)ahp, h1 = *(const bf16x8*)(ahp + 8);
        bf16x8 l0 = *(const bf16x8*)alp, l1 = *(const bf16x8*)(alp + 8);
        const float* wp = W + (size_t)(n0 + rw) * H_ + k0 + kw;
        float4 w0 = *(const float4*)wp, w1 = *(const float4*)(wp + 4);
        float wf[8] = {w0.x, w0.y, w0.z, w0.w, w1.x, w1.y, w1.z, w1.w};
        bf16x8 wh, wl;
        #pragma unroll
        for (int i = 0; i < 8; i++) { bh h, l; split2(wf[i], h, l); wh[i] = h; wl[i] = l; }
        __syncthreads();
        *(bf16x8*)&AhS[ra * LDK + ka] = h0;  *(bf16x8*)&AhS[ra * LDK + ka + 8] = h1;
        *(bf16x8*)&AlS[ra * LDK + ka] = l0;  *(bf16x8*)&AlS[ra * LDK + ka + 8] = l1;
        *(bf16x8*)&WhS[rw * LDK + kw] = wh;  *(bf16x8*)&WlS[rw * LDK + kw] = wl;
        __syncthreads();
        bf16x8 fah[2], fal[2], fwh[2], fwl[2];
        #pragma unroll
        for (int mi = 0; mi < 2; mi++) {
            int row = wm + mi * 16 + l15;
            fah[mi] = *(const bf16x8*)&AhS[row * LDK + q * 8];
            fal[mi] = *(const bf16x8*)&AlS[row * LDK + q * 8];
        }
        #pragma unroll
        for (int ni = 0; ni < 2; ni++) {
            int row = ni * 16 + l15;
            fwh[ni] = *(const bf16x8*)&WhS[row * LDK + q * 8];
            fwl[ni] = *(const bf16x8*)&WlS[row * LDK + q * 8];
        }
        #pragma unroll
        for (int mi = 0; mi < 2; mi++)
            #pragma unroll
            for (int ni = 0; ni < 2; ni++) {
                acc[mi][ni] = __builtin_amdgcn_mfma_f32_16x16x32_bf16(fah[mi], fwh[ni], acc[mi][ni], 0, 0, 0);
                acc[mi][ni] = __builtin_amdgcn_mfma_f32_16x16x32_bf16(fah[mi], fwl[ni], acc[mi][ni], 0, 0, 0);
                acc[mi][ni] = __builtin_amdgcn_mfma_f32_16x16x32_bf16(fal[mi], fwh[ni], acc[mi][ni], 0, 0, 0);
            }
    }
    #pragma unroll
    for (int ni = 0; ni < 2; ni++) {
        int col = n0 + ni * 16 + l15;
        float bb = bias[col];
        #pragma unroll
        for (int mi = 0; mi < 2; mi++)
            #pragma unroll
            for (int reg = 0; reg < 4; reg++) {
                int row = m0 + wm + mi * 16 + q * 4 + reg;
                C[(size_t)row * D_ + col] = acc[mi][ni][reg] + bb;
            }
    }
}

// ---------------- pairwise weighted L1 + mask + leaky (fp32, unchanged) ----------------
#define KC 16
#define LP 68
__global__ __launch_bounds__(256) void dist_kernel(const float* __restrict__ xhat,
                                                   const float* __restrict__ w,
                                                   const int* __restrict__ box_num,
                                                   float* __restrict__ dist) {
    __shared__ __align__(16) float Xi[KC * LP];
    __shared__ __align__(16) float Xj[KC * LP];
    const int b = blockIdx.z;
    const int i0 = blockIdx.y * 64, j0 = blockIdx.x * 64;
    const int tx = threadIdx.x & 15, ty = threadIdx.x >> 4;
    const int lane = threadIdx.x & 63;
    const int lr = threadIdx.x >> 2;
    const int lk = (threadIdx.x & 3) * 4;
    // per-wave sum(learn_w): learn_w >= 0 by construction
    float sumw = w[lane] + w[lane + 64] + w[lane + 128] + w[lane + 192];
    #pragma unroll
    for (int off = 32; off > 0; off >>= 1) sumw += __shfl_xor(sumw, off);

    const float* xb = xhat + (size_t)b * N_ * D_;
    const float* Xip = xb + (size_t)(i0 + lr) * D_ + lk;
    const float* Xjp = xb + (size_t)(j0 + lr) * D_ + lk;
    float acc[4][4] = {};
    for (int k0 = 0; k0 < D_; k0 += KC) {
        float4 xiv = *(const float4*)(Xip + k0);
        float4 xjv = *(const float4*)(Xjp + k0);
        float4 wv  = *(const float4*)(w + k0 + lk);
        xiv.x *= wv.x; xiv.y *= wv.y; xiv.z *= wv.z; xiv.w *= wv.w;
        xjv.x *= wv.x; xjv.y *= wv.y; xjv.z *= wv.z; xjv.w *= wv.w;
        __syncthreads();
        Xi[(lk + 0) * LP + lr] = xiv.x; Xi[(lk + 1) * LP + lr] = xiv.y;
        Xi[(lk + 2) * LP + lr] = xiv.z; Xi[(lk + 3) * LP + lr] = xiv.w;
        Xj[(lk + 0) * LP + lr] = xjv.x; Xj[(lk + 1) * LP + lr] = xjv.y;
        Xj[(lk + 2) * LP + lr] = xjv.z; Xj[(lk + 3) * LP + lr] = xjv.w;
        __syncthreads();
        #pragma unroll
        for (int kk = 0; kk < KC; kk++) {
            float4 a4 = *(const float4*)&Xi[kk * LP + ty * 4];
            float4 b4 = *(const float4*)&Xj[kk * LP + tx * 4];
            float a[4] = {a4.x, a4.y, a4.z, a4.w};
            float bb[4] = {b4.x, b4.y, b4.z, b4.w};
            #pragma unroll
            for (int ii = 0; ii < 4; ii++)
                #pragma unroll
                for (int jj = 0; jj < 4; jj++)
                    acc[ii][jj] += fabsf(a[ii] - bb[jj]);
        }
    }
    const int bn = load_boxnum(box_num, b);
    #pragma unroll
    for (int ii = 0; ii < 4; ii++) {
        int i = i0 + ty * 4 + ii;
        bool vi = i < bn;
        #pragma unroll
        for (int jj = 0; jj < 4; jj++) {
            int j = j0 + tx * 4 + jj;
            float v = acc[ii][jj];
            if (!(vi && (j < bn))) v -= sumw;
            v = v > 0.f ? v : 0.01f * v;
            dist[((size_t)b * N_ + i) * N_ + j] = v;
        }
    }
}

// ---------------- row softmax: one wave per (b,i) row ----------------
__global__ __launch_bounds__(64) void softmax_kernel(float* __restrict__ sa,
                                                     const float* __restrict__ adj) {
    const int row = blockIdx.x;
    const int t = threadIdx.x;
    float* prow = sa + (size_t)row * N_;
    const float* arow = adj + (size_t)row * N_;
    float v[6];
    float m = -1e30f;
    #pragma unroll
    for (int qq = 0; qq < 6; qq++) { v[qq] = prow[t + qq * 64]; m = fmaxf(m, v[qq]); }
    #pragma unroll
    for (int off = 32; off > 0; off >>= 1) m = fmaxf(m, __shfl_xor(m, off));
    float e[6];
    float s = 0.f;
    #pragma unroll
    for (int qq = 0; qq < 6; qq++) { e[qq] = arow[t + qq * 64] * expf(v[qq] - m); s += e[qq]; }
    #pragma unroll
    for (int off = 32; off > 0; off >>= 1) s += __shfl_xor(s, off);
    float inv = 1.0f / s;
    #pragma unroll
    for (int qq = 0; qq < 6; qq++) prow[t + qq * 64] = e[qq] * inv + 1e-10f;
}

extern "C" void kernel_launch(void* const* d_in, const int* in_sizes, int n_in,
                              void* d_out, int out_size, void* d_ws, size_t ws_size,
                              hipStream_t stream) {
    const float* x       = (const float*)d_in[0];
    const float* adj     = (const float*)d_in[1];
    const int*   box_num = (const int*)d_in[2];
    const float* fc1_w   = (const float*)d_in[3];
    const float* fc1_b   = (const float*)d_in[4];
    const float* fc2_w   = (const float*)d_in[5];
    const float* fc2_b   = (const float*)d_in[6];
    const float* learn_w = (const float*)d_in[7];

    float* soft_adj = (float*)d_out;
    float* xhat     = (float*)d_out + (size_t)B_ * N_ * N_;

    const int BN = B_ * N_;  // 3072
    // c1 scratch: hi + lo bf16, (max_rows x 1024) each; chunk if ws too small
    const size_t bytes_per_row = (size_t)H_ * 2 * 2;
    long long mr = (long long)(ws_size / bytes_per_row) & ~63LL;
    int max_rows = (int)((mr > BN) ? BN : mr);
    if (max_rows < 64) max_rows = 64;
    bh* c1h = (bh*)d_ws;
    bh* c1l = c1h + (size_t)max_rows * H_;

    for (int m0 = 0; m0 < BN; m0 += max_rows) {
        int rows = BN - m0; if (rows > max_rows) rows = max_rows;
        dim3 g1(H_ / 64, rows / 64);
        gemm1_kernel<<<g1, 256, 0, stream>>>(x + (size_t)m0 * D_, fc1_w, fc1_b, c1h, c1l);
        dim3 g2(D_ / 32, rows / 64);
        gemm2_kernel<<<g2, 128, 0, stream>>>(c1h, c1l, fc2_w, fc2_b, xhat + (size_t)m0 * D_);
    }

    dim3 gd(N_ / 64, N_ / 64, B_);
    dist_kernel<<<gd, 256, 0, stream>>>(xhat, learn_w, box_num, soft_adj);

    softmax_kernel<<<BN, 64, 0, stream>>>(soft_adj, adj);
}

// Round 4
// 140.650 us; speedup vs baseline: 1.3735x; 1.1154x over previous
//
#include <hip/hip_runtime.h>
#include <math.h>

// Problem constants (fixed by reference)
#define B_ 8
#define N_ 384
#define D_ 256
#define H_ 1024

typedef __bf16 bh;
typedef __bf16 bf16x8 __attribute__((ext_vector_type(8)));
typedef float  f32x4  __attribute__((ext_vector_type(4)));
typedef _Float16 h2 __attribute__((ext_vector_type(2)));

#define LDK 40   // LDS row stride in bf16 (32 data + 8 pad): 80 B = 5*16 B -> b128-aligned, 2-way banks (free)

#if __has_builtin(__builtin_amdgcn_fdot2)
#define FDOT2(a,b,c) __builtin_amdgcn_fdot2((a),(b),(c),false)
#else
#define FDOT2(a,b,c) ((c) + (float)(a).x*(float)(b).x + (float)(a).y*(float)(b).y)
#endif

__device__ inline h2 habs2(h2 x) {
    unsigned u = __builtin_bit_cast(unsigned, x) & 0x7fff7fffu;
    return __builtin_bit_cast(h2, u);
}

// split fp32 -> hi + lo bf16 (3xbf16 trick: a*b ~= ah*bh + ah*bl + al*bh, rel err ~2^-16)
__device__ inline void split2(float v, bh& h, bh& l) {
    h = (bh)v;
    l = (bh)(v - (float)h);
}

// box_num is logically int64; harness may hand int32. box_num >= 1 always, so
// int64-LE layout has all odd words zero -> runtime-detectable.
__device__ inline int load_boxnum(const int* __restrict__ p, int b) {
    bool is64 = ((p[1] | p[3] | p[5] | p[7]) == 0);
    return is64 ? p[2 * b] : p[b];
}

// ---------------- GEMM1: c1 = relu(x @ fc1_w^T + fc1_b), output split hi/lo bf16 ----------------
__global__ __launch_bounds__(256) void gemm1_kernel(
        const float* __restrict__ A,     // (rows,256) fp32
        const float* __restrict__ W,     // (1024,256) fp32
        const float* __restrict__ bias,  // (1024)
        bh* __restrict__ Ch, bh* __restrict__ Cl)  // (rows,1024) each
{
    __shared__ __align__(16) bh AhS[64 * LDK], AlS[64 * LDK], WhS[64 * LDK], WlS[64 * LDK];
    const int tid = threadIdx.x;
    const int m0 = blockIdx.y * 64, n0 = blockIdx.x * 64;
    const int r = tid >> 2, kq = (tid & 3) * 8;
    const int lane = tid & 63, wv_ = tid >> 6;
    const int wm = (wv_ & 1) * 32, wn = (wv_ >> 1) * 32;
    const int l15 = lane & 15, q = lane >> 4;

    f32x4 acc[2][2] = {};
    for (int k0 = 0; k0 < 256; k0 += 32) {
        const float* ap = A + (size_t)(m0 + r) * 256 + k0 + kq;
        const float* wp = W + (size_t)(n0 + r) * 256 + k0 + kq;
        float4 a0 = *(const float4*)ap;
        float4 a1 = *(const float4*)(ap + 4);
        float4 w0 = *(const float4*)wp;
        float4 w1 = *(const float4*)(wp + 4);
        float av[8] = {a0.x, a0.y, a0.z, a0.w, a1.x, a1.y, a1.z, a1.w};
        float wf[8] = {w0.x, w0.y, w0.z, w0.w, w1.x, w1.y, w1.z, w1.w};
        bf16x8 ah, al, wh, wl;
        #pragma unroll
        for (int i = 0; i < 8; i++) {
            bh h, l;
            split2(av[i], h, l); ah[i] = h; al[i] = l;
            split2(wf[i], h, l); wh[i] = h; wl[i] = l;
        }
        __syncthreads();
        *(bf16x8*)&AhS[r * LDK + kq] = ah;  *(bf16x8*)&AlS[r * LDK + kq] = al;
        *(bf16x8*)&WhS[r * LDK + kq] = wh;  *(bf16x8*)&WlS[r * LDK + kq] = wl;
        __syncthreads();
        bf16x8 fah[2], fal[2], fwh[2], fwl[2];
        #pragma unroll
        for (int mi = 0; mi < 2; mi++) {
            int row = wm + mi * 16 + l15;
            fah[mi] = *(const bf16x8*)&AhS[row * LDK + q * 8];
            fal[mi] = *(const bf16x8*)&AlS[row * LDK + q * 8];
        }
        #pragma unroll
        for (int ni = 0; ni < 2; ni++) {
            int row = wn + ni * 16 + l15;
            fwh[ni] = *(const bf16x8*)&WhS[row * LDK + q * 8];
            fwl[ni] = *(const bf16x8*)&WlS[row * LDK + q * 8];
        }
        #pragma unroll
        for (int mi = 0; mi < 2; mi++)
            #pragma unroll
            for (int ni = 0; ni < 2; ni++) {
                acc[mi][ni] = __builtin_amdgcn_mfma_f32_16x16x32_bf16(fah[mi], fwh[ni], acc[mi][ni], 0, 0, 0);
                acc[mi][ni] = __builtin_amdgcn_mfma_f32_16x16x32_bf16(fah[mi], fwl[ni], acc[mi][ni], 0, 0, 0);
                acc[mi][ni] = __builtin_amdgcn_mfma_f32_16x16x32_bf16(fal[mi], fwh[ni], acc[mi][ni], 0, 0, 0);
            }
    }
    #pragma unroll
    for (int ni = 0; ni < 2; ni++) {
        int col = n0 + wn + ni * 16 + l15;
        float bb = bias[col];
        #pragma unroll
        for (int mi = 0; mi < 2; mi++)
            #pragma unroll
            for (int reg = 0; reg < 4; reg++) {
                int row = m0 + wm + mi * 16 + q * 4 + reg;
                float v = fmaxf(acc[mi][ni][reg] + bb, 0.f);
                bh h, l; split2(v, h, l);
                size_t off = (size_t)row * H_ + col;
                Ch[off] = h; Cl[off] = l;
            }
    }
}

// ---------------- GEMM2: xhat = c1 @ fc2_w^T + fc2_b, fp32 out ----------------
__global__ __launch_bounds__(128) void gemm2_kernel(
        const bh* __restrict__ Ah_, const bh* __restrict__ Al_,  // (rows,1024)
        const float* __restrict__ W,     // (256,1024) fp32
        const float* __restrict__ bias,  // (256)
        float* __restrict__ C)           // (rows,256)
{
    __shared__ __align__(16) bh AhS[64 * LDK], AlS[64 * LDK], WhS[32 * LDK], WlS[32 * LDK];
    const int tid = threadIdx.x;
    const int m0 = blockIdx.y * 64, n0 = blockIdx.x * 32;
    const int lane = tid & 63, wv_ = tid >> 6;
    const int wm = wv_ * 32;
    const int l15 = lane & 15, q = lane >> 4;
    const int ra = tid >> 1, ka = (tid & 1) * 16;
    const int rw = tid >> 2, kw = (tid & 3) * 8;

    f32x4 acc[2][2] = {};
    for (int k0 = 0; k0 < 1024; k0 += 32) {
        const bh* ahp = Ah_ + (size_t)(m0 + ra) * H_ + k0 + ka;
        const bh* alp = Al_ + (size_t)(m0 + ra) * H_ + k0 + ka;
        bf16x8 h0 = *(const bf16x8*)ahp, h1 = *(const bf16x8*)(ahp + 8);
        bf16x8 l0 = *(const bf16x8*)alp, l1 = *(const bf16x8*)(alp + 8);
        const float* wp = W + (size_t)(n0 + rw) * H_ + k0 + kw;
        float4 w0 = *(const float4*)wp, w1 = *(const float4*)(wp + 4);
        float wf[8] = {w0.x, w0.y, w0.z, w0.w, w1.x, w1.y, w1.z, w1.w};
        bf16x8 wh, wl;
        #pragma unroll
        for (int i = 0; i < 8; i++) { bh h, l; split2(wf[i], h, l); wh[i] = h; wl[i] = l; }
        __syncthreads();
        *(bf16x8*)&AhS[ra * LDK + ka] = h0;  *(bf16x8*)&AhS[ra * LDK + ka + 8] = h1;
        *(bf16x8*)&AlS[ra * LDK + ka] = l0;  *(bf16x8*)&AlS[ra * LDK + ka + 8] = l1;
        *(bf16x8*)&WhS[rw * LDK + kw] = wh;  *(bf16x8*)&WlS[rw * LDK + kw] = wl;
        __syncthreads();
        bf16x8 fah[2], fal[2], fwh[2], fwl[2];
        #pragma unroll
        for (int mi = 0; mi < 2; mi++) {
            int row = wm + mi * 16 + l15;
            fah[mi] = *(const bf16x8*)&AhS[row * LDK + q * 8];
            fal[mi] = *(const bf16x8*)&AlS[row * LDK + q * 8];
        }
        #pragma unroll
        for (int ni = 0; ni < 2; ni++) {
            int row = ni * 16 + l15;
            fwh[ni] = *(const bf16x8*)&WhS[row * LDK + q * 8];
            fwl[ni] = *(const bf16x8*)&WlS[row * LDK + q * 8];
        }
        #pragma unroll
        for (int mi = 0; mi < 2; mi++)
            #pragma unroll
            for (int ni = 0; ni < 2; ni++) {
                acc[mi][ni] = __builtin_amdgcn_mfma_f32_16x16x32_bf16(fah[mi], fwh[ni], acc[mi][ni], 0, 0, 0);
                acc[mi][ni] = __builtin_amdgcn_mfma_f32_16x16x32_bf16(fah[mi], fwl[ni], acc[mi][ni], 0, 0, 0);
                acc[mi][ni] = __builtin_amdgcn_mfma_f32_16x16x32_bf16(fal[mi], fwh[ni], acc[mi][ni], 0, 0, 0);
            }
    }
    #pragma unroll
    for (int ni = 0; ni < 2; ni++) {
        int col = n0 + ni * 16 + l15;
        float bb = bias[col];
        #pragma unroll
        for (int mi = 0; mi < 2; mi++)
            #pragma unroll
            for (int reg = 0; reg < 4; reg++) {
                int row = m0 + wm + mi * 16 + q * 4 + reg;
                C[(size_t)row * D_ + col] = acc[mi][ni][reg] + bb;
            }
    }
}

// ---------------- pairwise weighted L1 + mask + leaky: symmetric fp16-dot2 version ----------------
// Upper-triangle 64x64 tiles only (21 per batch, 168 blocks), mirror-written.
// dist[b,i,j] = leaky( sum_d w_d*|xh_i - xh_j| - (invalid ? sumw : 0) ); symmetric in (i,j).
#define DLP 68   // LDS row stride in half2 units (64 rows + 4 pad); 68*4B=272B, 16B-aligned
__global__ __launch_bounds__(256) void dist_kernel(const float* __restrict__ xhat,
                                                   const float* __restrict__ w,
                                                   const int* __restrict__ box_num,
                                                   float* __restrict__ dist) {
    __shared__ __align__(16) unsigned XiU[16 * DLP];
    __shared__ __align__(16) unsigned XjU[16 * DLP];
    const int bidx = blockIdx.x;
    const int b = bidx / 21;
    int p = bidx % 21;
    int ti = 0;
    while (p >= 6 - ti) { p -= 6 - ti; ti++; }
    const int tj = ti + p;
    const int i0 = ti * 64, j0 = tj * 64;

    const int tid = threadIdx.x;
    const int tx = tid & 15, ty = tid >> 4;       // 16x16 thread grid, 4x4 micro
    const int lane = tid & 63;
    const int r = tid >> 2, kq = (tid & 3) * 8;   // staging: row, k-offset
    const int kq2 = (tid & 3) * 4;                // k2-offset

    // sum(learn_w) per wave
    float sumw = w[lane] + w[lane + 64] + w[lane + 128] + w[lane + 192];
    #pragma unroll
    for (int off = 32; off > 0; off >>= 1) sumw += __shfl_xor(sumw, off);

    const float* xb = xhat + (size_t)b * N_ * D_;
    float acc[4][4] = {};

    for (int k0 = 0; k0 < D_; k0 += 32) {
        // per-chunk w pairs (wave-uniform scalar loads)
        h2 wk2[16];
        #pragma unroll
        for (int c = 0; c < 16; c++) {
            float2 wp = *(const float2*)&w[k0 + 2 * c];
            wk2[c] = (h2){(_Float16)wp.x, (_Float16)wp.y};
        }
        const float* ip = xb + (size_t)(i0 + r) * D_ + k0 + kq;
        const float* jp = xb + (size_t)(j0 + r) * D_ + k0 + kq;
        float4 i0v = *(const float4*)ip, i1v = *(const float4*)(ip + 4);
        float4 j0v = *(const float4*)jp, j1v = *(const float4*)(jp + 4);
        float fi[8] = {i0v.x, i0v.y, i0v.z, i0v.w, i1v.x, i1v.y, i1v.z, i1v.w};
        float fj[8] = {j0v.x, j0v.y, j0v.z, j0v.w, j1v.x, j1v.y, j1v.z, j1v.w};
        __syncthreads();
        #pragma unroll
        for (int c = 0; c < 4; c++) {
            h2 hi = (h2){(_Float16)fi[2 * c], (_Float16)fi[2 * c + 1]};
            h2 hj = (h2){(_Float16)fj[2 * c], (_Float16)fj[2 * c + 1]};
            XiU[(kq2 + c) * DLP + r] = __builtin_bit_cast(unsigned, hi);
            XjU[(kq2 + c) * DLP + r] = __builtin_bit_cast(unsigned, hj);
        }
        __syncthreads();
        #pragma unroll
        for (int k2 = 0; k2 < 16; k2++) {
            uint4 ar = *(const uint4*)&XiU[k2 * DLP + ty * 4];   // 4 i-rows (broadcast x16)
            uint4 br = *(const uint4*)&XjU[k2 * DLP + tx * 4];   // 4 j-rows
            h2 ai[4] = {__builtin_bit_cast(h2, ar.x), __builtin_bit_cast(h2, ar.y),
                        __builtin_bit_cast(h2, ar.z), __builtin_bit_cast(h2, ar.w)};
            h2 bj[4] = {__builtin_bit_cast(h2, br.x), __builtin_bit_cast(h2, br.y),
                        __builtin_bit_cast(h2, br.z), __builtin_bit_cast(h2, br.w)};
            h2 wv = wk2[k2];
            #pragma unroll
            for (int ii = 0; ii < 4; ii++)
                #pragma unroll
                for (int jj = 0; jj < 4; jj++) {
                    h2 d = habs2(ai[ii] - bj[jj]);
                    acc[ii][jj] = FDOT2(d, wv, acc[ii][jj]);
                }
        }
    }

    const int bn = load_boxnum(box_num, b);
    float m[4][4];
    #pragma unroll
    for (int ii = 0; ii < 4; ii++) {
        int i = i0 + ty * 4 + ii;
        bool vi = i < bn;
        #pragma unroll
        for (int jj = 0; jj < 4; jj++) {
            int j = j0 + tx * 4 + jj;
            float v = acc[ii][jj];
            if (!(vi && (j < bn))) v -= sumw;
            m[ii][jj] = v > 0.f ? v : 0.01f * v;
        }
    }
    // primary tile: rows i, cols j (coalesced float4)
    #pragma unroll
    for (int ii = 0; ii < 4; ii++) {
        int i = i0 + ty * 4 + ii;
        float4 o = {m[ii][0], m[ii][1], m[ii][2], m[ii][3]};
        *(float4*)&dist[((size_t)b * N_ + i) * N_ + j0 + tx * 4] = o;
    }
    // mirror tile: rows j, cols i (diagonal tiles double-write identical bits - benign)
    #pragma unroll
    for (int jj = 0; jj < 4; jj++) {
        int j = j0 + tx * 4 + jj;
        float4 o = {m[0][jj], m[1][jj], m[2][jj], m[3][jj]};
        *(float4*)&dist[((size_t)b * N_ + j) * N_ + i0 + ty * 4] = o;
    }
}

// ---------------- row softmax: 4 waves per block, one row per wave ----------------
__global__ __launch_bounds__(256) void softmax_kernel(float* __restrict__ sa,
                                                      const float* __restrict__ adj) {
    const int row = blockIdx.x * 4 + (threadIdx.x >> 6);
    const int t = threadIdx.x & 63;
    float* prow = sa + (size_t)row * N_;
    const float* arow = adj + (size_t)row * N_;
    float v[6];
    float m = -1e30f;
    #pragma unroll
    for (int qq = 0; qq < 6; qq++) { v[qq] = prow[t + qq * 64]; m = fmaxf(m, v[qq]); }
    #pragma unroll
    for (int off = 32; off > 0; off >>= 1) m = fmaxf(m, __shfl_xor(m, off));
    float e[6];
    float s = 0.f;
    #pragma unroll
    for (int qq = 0; qq < 6; qq++) { e[qq] = arow[t + qq * 64] * expf(v[qq] - m); s += e[qq]; }
    #pragma unroll
    for (int off = 32; off > 0; off >>= 1) s += __shfl_xor(s, off);
    float inv = 1.0f / s;
    #pragma unroll
    for (int qq = 0; qq < 6; qq++) prow[t + qq * 64] = e[qq] * inv + 1e-10f;
}

extern "C" void kernel_launch(void* const* d_in, const int* in_sizes, int n_in,
                              void* d_out, int out_size, void* d_ws, size_t ws_size,
                              hipStream_t stream) {
    const float* x       = (const float*)d_in[0];
    const float* adj     = (const float*)d_in[1];
    const int*   box_num = (const int*)d_in[2];
    const float* fc1_w   = (const float*)d_in[3];
    const float* fc1_b   = (const float*)d_in[4];
    const float* fc2_w   = (const float*)d_in[5];
    const float* fc2_b   = (const float*)d_in[6];
    const float* learn_w = (const float*)d_in[7];

    float* soft_adj = (float*)d_out;
    float* xhat     = (float*)d_out + (size_t)B_ * N_ * N_;

    const int BN = B_ * N_;  // 3072
    const size_t bytes_per_row = (size_t)H_ * 2 * 2;
    long long mr = (long long)(ws_size / bytes_per_row) & ~63LL;
    int max_rows = (int)((mr > BN) ? BN : mr);
    if (max_rows < 64) max_rows = 64;
    bh* c1h = (bh*)d_ws;
    bh* c1l = c1h + (size_t)max_rows * H_;

    for (int m0 = 0; m0 < BN; m0 += max_rows) {
        int rows = BN - m0; if (rows > max_rows) rows = max_rows;
        dim3 g1(H_ / 64, rows / 64);
        gemm1_kernel<<<g1, 256, 0, stream>>>(x + (size_t)m0 * D_, fc1_w, fc1_b, c1h, c1l);
        dim3 g2(D_ / 32, rows / 64);
        gemm2_kernel<<<g2, 128, 0, stream>>>(c1h, c1l, fc2_w, fc2_b, xhat + (size_t)m0 * D_);
    }

    dist_kernel<<<B_ * 21, 256, 0, stream>>>(xhat, learn_w, box_num, soft_adj);

    softmax_kernel<<<BN / 4, 256, 0, stream>>>(soft_adj, adj);
}